// Round 12
// baseline (388.748 us; speedup 1.0000x reference)
//
#include <hip/hip_runtime.h>
#include <stdint.h>

// Problem constants
#define N_ROWS 16384   // 16*1024 flattened input rows
#define N_EMB  8192    // codebook size
#define C_DIM  256     // embedding dim
#define NKT    8       // pure-bf16 GEMM: K=256, 8 K-tiles of 32 (R9-validated)
#define NCHUNK 4       // row-space chunks: 134 MB of distances per chunk -> L3-resident

// d_out layout (float element offsets), outputs concatenated in return order:
// loss(1), quantized_st(16*1024*3*256), perplexity(1), encoding_indices(16384*3), distances(16384*8192)
#define OFF_LOSS 0ull
#define OFF_Q    1ull
#define OFF_PERP 12582913ull
#define OFF_IDX  12582914ull
#define OFF_DIST 12632066ull

typedef short bf16x8 __attribute__((ext_vector_type(8)));
typedef float f32x4  __attribute__((ext_vector_type(4)));
typedef float f32x2  __attribute__((ext_vector_type(2)));

// ---------------- prep: fp32 -> bf16 (rne), K-chunk-major layout + fp32 row norms ----------------
__device__ __forceinline__ unsigned short f2bf_rne(float f){
  unsigned u = __float_as_uint(f);
  unsigned r = 0x7fffu + ((u >> 16) & 1u);
  return (unsigned short)((u + r) >> 16);
}

__global__ __launch_bounds__(256) void k_prep(
    const float* __restrict__ X, const float* __restrict__ E,
    short* __restrict__ XT, short* __restrict__ ET,
    float* __restrict__ xnorm, float* __restrict__ enorm)
{
  int b = blockIdx.x; int tid = threadIdx.x;
  const float* src; short* dst; float* nrm; int r0, NR;
  if (b < N_ROWS / 8){ r0 = b * 8;                src = X; dst = XT; nrm = xnorm; NR = N_ROWS; }
  else               { r0 = (b - N_ROWS / 8) * 8; src = E; dst = ET; nrm = enorm; NR = N_EMB;  }
  int e = tid & 7, rsub = (tid >> 3) & 7, qg = tid >> 6;   // 8e x 8row x 4qg
  int row = r0 + rsub;
  float s = 0.f;
  #pragma unroll
  for (int qq = 0; qq < 8; qq++){
    int q = qg * 8 + qq;                 // k-chunk [0,32) covering K=256
    float x = src[(size_t)row * C_DIM + q * 8 + e];
    dst[((size_t)q * NR + row) * 8 + e] = (short)f2bf_rne(x);
    s += x * x;
  }
  __shared__ float red[8][33];
  red[rsub][qg * 8 + e] = s;
  __syncthreads();
  if (tid < 8){
    float t = 0.f;
    #pragma unroll
    for (int i = 0; i < 32; i++) t += red[tid][i];
    nrm[r0 + tid] = t;
  }
}

// ---------------- GEMM: BM=256 BN=256 BK=32, 8 waves; chunked over bm for L3 residency ----------------
// R11-exact loop. LDS 64 KB; launch_bounds(512,2): VGPR=128 no spill -> 2 blocks/CU.
// Fused top-k REJECTED (R4 shfl storm, R10 code-bloat stall); the re-read is served from L3 instead.
__device__ __forceinline__ void gload16(void* lds, const void* g){
  __builtin_amdgcn_global_load_lds(
      (const __attribute__((address_space(1))) void*)g,
      (__attribute__((address_space(3))) void*)lds, 16, 0, 0);
}

__global__ __launch_bounds__(512, 2) void k_gemm(
    const short* __restrict__ XT, const short* __restrict__ ET,
    const float* __restrict__ xnorm, const float* __restrict__ enorm,
    float* __restrict__ out, int bm0)
{
  // LDS: [buf][q=0..3][row 0..255][8 bf16]; 16 KB per matrix per buffer = 64 KB total
  __shared__ __align__(16) short As[2][4 * 256 * 8];
  __shared__ __align__(16) short Bs[2][4 * 256 * 8];
  int tid = threadIdx.x;
  int lane = tid & 63, w = tid >> 6;
  int wr = w >> 2, wc = w & 3;          // wave grid 2M x 4N; wave-tile 128 x 64
  // Per-chunk swizzle (512 blocks = 16 bm x 32 bn): XCD x owns bn in [4x,4x+4), L2-resident B.
  int id = blockIdx.x;
  int x = id & 7, j = id >> 3, c = j >> 4, u = j & 15;
  int bm = bm0 + c * 4 + (u >> 2);      // chunk-local 16 bm tiles
  int bn = x * 4 + (u & 3);             // [0,32)

  f32x4 acc[8][4];
  #pragma unroll
  for (int m = 0; m < 8; m++)
    #pragma unroll
    for (int n = 0; n < 4; n++) acc[m][n] = (f32x4){0.f, 0.f, 0.f, 0.f};

  // staging one K-tile (K=32) = 32 wave-gloads (A: 4q x 4 quarters, B: same); wave w takes 4
  auto stage = [&](int buf, int kt){
    #pragma unroll
    for (int i = 0; i < 4; i++){
      int p = w * 4 + i;                // wave-uniform
      if (p < 16){
        int q = p >> 2, qr = p & 3;
        gload16(&As[buf][(q * 256 + qr * 64) * 8],
                XT + ((size_t)(kt * 4 + q) * N_ROWS + (size_t)bm * 256 + qr * 64 + lane) * 8);
      } else {
        int pb = p - 16; int q = pb >> 2, qr = pb & 3;
        gload16(&Bs[buf][(q * 256 + qr * 64) * 8],
                ET + ((size_t)(kt * 4 + q) * N_EMB + (size_t)bn * 256 + qr * 64 + lane) * 8);
      }
    }
  };

  int r15 = lane & 15, lg4 = lane >> 4;

  stage(0, 0); stage(1, 1);             // 8 loads/wave in flight

  #pragma unroll
  for (int t = 0; t < NKT; ++t){
    const int buf = t & 1;
    if (t < NKT - 1) { asm volatile("s_waitcnt vmcnt(4)" ::: "memory"); }
    else             { asm volatile("s_waitcnt vmcnt(0)" ::: "memory"); }
    __builtin_amdgcn_s_barrier();       // barrier 1: tile t fully in LDS

    bf16x8 af[8], bf[4];
    {
      int q = lg4;
      #pragma unroll
      for (int m = 0; m < 8; m++)
        af[m] = *(const bf16x8*)&As[buf][(q * 256 + wr * 128 + m * 16 + r15) * 8];
      #pragma unroll
      for (int n = 0; n < 4; n++)
        bf[n] = *(const bf16x8*)&Bs[buf][(q * 256 + wc * 64 + n * 16 + r15) * 8];
    }
    __builtin_amdgcn_s_setprio(1);
    #pragma unroll
    for (int m = 0; m < 4; m++)
      #pragma unroll
      for (int n = 0; n < 4; n++)
        acc[m][n] = __builtin_amdgcn_mfma_f32_16x16x32_bf16(af[m], bf[n], acc[m][n], 0, 0, 0);
    __builtin_amdgcn_s_setprio(0);

    asm volatile("s_waitcnt lgkmcnt(0)" ::: "memory");
    __builtin_amdgcn_sched_barrier(0);
    __builtin_amdgcn_s_barrier();       // barrier 2: all waves done reading buf
    if (t < NKT - 2) stage(buf, t + 2);

    __builtin_amdgcn_s_setprio(1);
    #pragma unroll
    for (int m = 4; m < 8; m++)
      #pragma unroll
      for (int n = 0; n < 4; n++)
        acc[m][n] = __builtin_amdgcn_mfma_f32_16x16x32_bf16(af[m], bf[n], acc[m][n], 0, 0, 0);
    __builtin_amdgcn_s_setprio(0);
  }

  // epilogue: dist = ||x||^2 + ||e||^2 - 2*dot  (C/D map: col=lane&15, row=(lane>>4)*4+j)
  int lc = lane & 15;
  #pragma unroll
  for (int m = 0; m < 8; m++){
    int rb = bm * 256 + wr * 128 + m * 16 + lg4 * 4;
    float xn0 = xnorm[rb], xn1 = xnorm[rb+1], xn2 = xnorm[rb+2], xn3 = xnorm[rb+3];
    #pragma unroll
    for (int n = 0; n < 4; n++){
      int col = bn * 256 + wc * 64 + n * 16 + lc;
      float en = enorm[col];
      out[OFF_DIST + (size_t)(rb + 0) * N_EMB + col] = xn0 + en - 2.0f * acc[m][n][0];
      out[OFF_DIST + (size_t)(rb + 1) * N_EMB + col] = xn1 + en - 2.0f * acc[m][n][1];
      out[OFF_DIST + (size_t)(rb + 2) * N_EMB + col] = xn2 + en - 2.0f * acc[m][n][2];
      out[OFF_DIST + (size_t)(rb + 3) * N_EMB + col] = xn3 + en - 2.0f * acc[m][n][3];
    }
  }
}

// ---------------- top-3 per row + quantize + loss partial (fused; tie-break = jax.lax.top_k) ----------------
// Plain (cached) loads on purpose: the chunk's distances were just written -> L3-resident.
#define LT(av,ai,bv,bi) (((av) < (bv)) || ((av) == (bv) && (ai) < (bi)))

__global__ __launch_bounds__(256) void k_tq(
    const float* __restrict__ X, const float* __restrict__ E,
    float* out, int* __restrict__ counts, float* __restrict__ partials, int row0)
{
  int row = row0 + blockIdx.x; int tid = threadIdx.x;
  const f32x4* drow = (const f32x4*)(out + OFF_DIST + (size_t)row * N_EMB);
  float v0 = __builtin_inff(), v1 = __builtin_inff(), v2 = __builtin_inff();
  int   i0 = 0x7fffffff,       i1 = 0x7fffffff,       i2 = 0x7fffffff;
  for (int i = tid; i < N_EMB / 4; i += 256){
    f32x4 dv = drow[i];
    #pragma unroll
    for (int j = 0; j < 4; j++){
      float d = dv[j]; int ii = i * 4 + j;
      if (LT(d, ii, v2, i2)){
        if (LT(d, ii, v1, i1)){
          v2 = v1; i2 = i1;
          if (LT(d, ii, v0, i0)){ v1 = v0; i1 = i0; v0 = d; i0 = ii; }
          else                  { v1 = d;  i1 = ii; }
        } else { v2 = d; i2 = ii; }
      }
    }
  }
  // wave butterfly merge of sorted triples
  #pragma unroll
  for (int off = 1; off < 64; off <<= 1){
    float b0 = __shfl_xor(v0, off), b1 = __shfl_xor(v1, off), b2 = __shfl_xor(v2, off);
    int   j0 = __shfl_xor(i0, off), j1 = __shfl_xor(i1, off), j2 = __shfl_xor(i2, off);
    float a0 = v0, a1 = v1, a2 = v2; int x0 = i0, x1 = i1, x2 = i2;
    float r0, r1, r2; int s0, s1, s2;
    if (LT(a0, x0, b0, j0)){ r0 = a0; s0 = x0; a0 = a1; x0 = x1; a1 = a2; x1 = x2; a2 = __builtin_inff(); x2 = 0x7fffffff; }
    else                   { r0 = b0; s0 = j0; b0 = b1; j0 = j1; b1 = b2; j1 = j2; b2 = __builtin_inff(); j2 = 0x7fffffff; }
    if (LT(a0, x0, b0, j0)){ r1 = a0; s1 = x0; a0 = a1; x0 = x1; a1 = a2; x1 = x2; a2 = __builtin_inff(); x2 = 0x7fffffff; }
    else                   { r1 = b0; s1 = j0; b0 = b1; j0 = j1; b1 = b2; j1 = j2; b2 = __builtin_inff(); j2 = 0x7fffffff; }
    if (LT(a0, x0, b0, j0)){ r2 = a0; s2 = x0; }
    else                   { r2 = b0; s2 = j0; }
    v0 = r0; i0 = s0; v1 = r1; i1 = s1; v2 = r2; i2 = s2;
  }
  __shared__ float swv[4][3]; __shared__ int swi[4][3];
  int lane = tid & 63, wid = tid >> 6;
  if (lane == 0){
    swv[wid][0] = v0; swv[wid][1] = v1; swv[wid][2] = v2;
    swi[wid][0] = i0; swi[wid][1] = i1; swi[wid][2] = i2;
  }
  __syncthreads();
  if (tid == 0){
    for (int wq = 1; wq < 4; wq++){
      for (int t = 0; t < 3; t++){
        float d = swv[wq][t]; int i = swi[wq][t];
        if (LT(d, i, v2, i2)){
          if (LT(d, i, v1, i1)){
            v2 = v1; i2 = i1;
            if (LT(d, i, v0, i0)){ v1 = v0; i1 = i0; v0 = d; i0 = i; }
            else                 { v1 = d;  i1 = i; }
          } else { v2 = d; i2 = i; }
        }
      }
    }
    out[OFF_IDX + (size_t)row * 3 + 0] = (float)i0;
    out[OFF_IDX + (size_t)row * 3 + 1] = (float)i1;
    out[OFF_IDX + (size_t)row * 3 + 2] = (float)i2;
    swi[0][0] = i0; swi[0][1] = i1; swi[0][2] = i2;   // broadcast final triple
    atomicAdd(&counts[i0], 1); atomicAdd(&counts[i1], 1); atomicAdd(&counts[i2], 1);
  }
  __syncthreads();
  // quantize + straight-through + loss partial (literal STE: x + (e - x)); c = tid
  int fi0 = swi[0][0], fi1 = swi[0][1], fi2 = swi[0][2];
  float xv = X[(size_t)row * C_DIM + tid];
  float lsum = 0.f;
  {
    float e = E[(size_t)fi0 * C_DIM + tid]; float d = e - xv;
    out[OFF_Q + ((size_t)row * 3 + 0) * C_DIM + tid] = xv + d; lsum += d * d;
  }
  {
    float e = E[(size_t)fi1 * C_DIM + tid]; float d = e - xv;
    out[OFF_Q + ((size_t)row * 3 + 1) * C_DIM + tid] = xv + d; lsum += d * d;
  }
  {
    float e = E[(size_t)fi2 * C_DIM + tid]; float d = e - xv;
    out[OFF_Q + ((size_t)row * 3 + 2) * C_DIM + tid] = xv + d; lsum += d * d;
  }
  __shared__ float qred[256];
  qred[tid] = lsum; __syncthreads();
  for (int s = 128; s > 0; s >>= 1){ if (tid < s) qred[tid] += qred[tid + s]; __syncthreads(); }
  if (tid == 0) partials[row] = qred[0];
}

// ---------------- scalars: loss + perplexity ----------------
__global__ __launch_bounds__(256) void k_final(
    const float* __restrict__ partials, const int* __restrict__ counts,
    float* __restrict__ out)
{
  int t = threadIdx.x;
  float ls = 0.f;
  for (int i = t; i < N_ROWS; i += 256) ls += partials[i];
  float es = 0.f;
  for (int i = t; i < N_EMB; i += 256){
    float p = (float)counts[i] * (1.0f / 16384.0f);
    es += p * logf(p + 1e-10f);
  }
  __shared__ float r1[256], r2[256];
  r1[t] = ls; r2[t] = es; __syncthreads();
  for (int s = 128; s > 0; s >>= 1){
    if (t < s){ r1[t] += r1[t + s]; r2[t] += r2[t + s]; }
    __syncthreads();
  }
  if (t == 0){
    out[OFF_LOSS] = 0.25f * r1[0] / 12582912.0f;
    out[OFF_PERP] = expf(-r2[0]);
  }
}

extern "C" void kernel_launch(void* const* d_in, const int* in_sizes, int n_in,
                              void* d_out, int out_size, void* d_ws, size_t ws_size,
                              hipStream_t stream)
{
  const float* X = (const float*)d_in[0];
  const float* E = (const float*)d_in[1];
  float* out = (float*)d_out;
  char* ws = (char*)d_ws;
  // ws layout (bytes), total ~12.8 MB
  short* XT       = (short*)(ws + 0);          // 8388608   (K-chunk-major bf16)
  short* ET       = (short*)(ws + 8388608);    // 4194304   (K-chunk-major bf16)
  float* xnorm    = (float*)(ws + 12582912);   // 65536
  float* enorm    = (float*)(ws + 12648448);   // 32768
  int*   counts   = (int*)  (ws + 12681216);   // 32768
  float* partials = (float*)(ws + 12713984);   // 65536

  hipMemsetAsync(counts, 0, N_EMB * sizeof(int), stream);
  k_prep<<<(N_ROWS + N_EMB) / 8, 256, 0, stream>>>(X, E, XT, ET, xnorm, enorm);
  // Chunked G->T interleave: each chunk's 134 MB distance slab stays L3-resident for the T pass.
  for (int ch = 0; ch < NCHUNK; ch++){
    k_gemm<<<512, 512, 0, stream>>>(XT, ET, xnorm, enorm, out, ch * (64 / NCHUNK));
    k_tq<<<N_ROWS / NCHUNK, 256, 0, stream>>>(X, E, out, counts, partials,
                                              ch * (N_ROWS / NCHUNK));
  }
  k_final<<<1, 256, 0, stream>>>(partials, counts, out);
}